// Round 6
// baseline (54.459 us; speedup 1.0000x reference)
//
#include <hip/hip_runtime.h>
#include <math.h>

#define NN 384
#define DD 128
#define EPSF 1e-6f
#define NB2 144            // fused-kernel grid (>= 78 tile blocks, covers 384 outputs in 3 reps)
#define NT2 384
#define TS 32              // invd tile
#define NTG (NN / TS)      // 12
#define STR 136            // LDS row stride (136%8==0 -> 16B aligned; 2-way-free bank pattern)

// K1: B = X G^T, A = B G, prod[i]=|B_i|^2 (= x M x), p2[i]=|A_i|^2 (= x M^T M x),
//     and block 0 zeroes the grid-barrier counter for the fused kernel.
__global__ void __launch_bounds__(128) k_A(const float* __restrict__ X,
                                           const float* __restrict__ G,
                                           float* __restrict__ B,
                                           float* __restrict__ A,
                                           float* __restrict__ prod,
                                           float* __restrict__ p2,
                                           int* __restrict__ bar) {
    __shared__ float Xi[DD];
    __shared__ float Bs[DD];
    __shared__ float rp[2], rq[2];
    const int i = blockIdx.x;
    const int t = threadIdx.x;

    if (i == 0 && t == 0)
        __hip_atomic_store(bar, 0, __ATOMIC_RELAXED, __HIP_MEMORY_SCOPE_AGENT);

    if (t < DD / 4) ((float4*)Xi)[t] = ((const float4*)(X + (size_t)i * DD))[t];
    __syncthreads();

    // B[i][t] = sum_d X[i][d] * G[t][d]
    float b = 0.f;
    const float* gr = G + (size_t)t * DD;
#pragma unroll
    for (int d = 0; d < DD; d += 4) {
        float4 g = *(const float4*)(gr + d);
        b = fmaf(g.x, Xi[d + 0], b);
        b = fmaf(g.y, Xi[d + 1], b);
        b = fmaf(g.z, Xi[d + 2], b);
        b = fmaf(g.w, Xi[d + 3], b);
    }
    Bs[t] = b;
    B[(size_t)i * DD + t] = b;
    __syncthreads();

    // A[i][t] = sum_c B[i][c] * G[c][t]   (coalesced G reads)
    float a = 0.f;
#pragma unroll 8
    for (int c = 0; c < DD; ++c)
        a = fmaf(Bs[c], G[(size_t)c * DD + t], a);
    A[(size_t)i * DD + t] = a;

    float pp = b * b, qq = a * a;
#pragma unroll
    for (int off = 32; off > 0; off >>= 1) {
        pp += __shfl_down(pp, off);
        qq += __shfl_down(qq, off);
    }
    if ((t & 63) == 0) { rp[t >> 6] = pp; rq[t >> 6] = qq; }
    __syncthreads();
    if (t == 0) { prod[i] = rp[0] + rp[1]; p2[i] = rq[0] + rq[1]; }
}

// K2 (fused): Phase A builds invd (upper-tri 32x32 tiles + mirrored stores, AGENT-scope
// atomics so it is visible across XCDs). Hand-rolled grid barrier. Phase B: per output
// row i, csmd row computed on the fly from B, then the cube max/min reduction.
__global__ void __launch_bounds__(NT2) k_fused(const float* __restrict__ B,
                                               const float* __restrict__ A,
                                               const float* __restrict__ prod,
                                               const float* __restrict__ p2,
                                               const int* __restrict__ y,
                                               float* __restrict__ invd,
                                               int* __restrict__ bar,
                                               float* __restrict__ out) {
    __shared__ float Ais[TS][STR], Aks[TS][STR];
    __shared__ float Tvs[TS][TS + 1];
    __shared__ float Bsr[DD];
    __shared__ float cvals[NN];
    __shared__ int   jidx[NN];
    __shared__ float red[NT2];
    __shared__ int   cnt;
    const int t = threadIdx.x;
    const int bidx = blockIdx.x;

    // ================= Phase A: invd tiles =================
    const int ti = bidx / NTG, tk = bidx % NTG;
    if (bidx < NTG * NTG && ti <= tk) {
        const int i0 = ti * TS, k0 = tk * TS;
        for (int idx = t; idx < TS * (DD / 4); idx += NT2) {
            const int r = idx >> 5, q = (idx & 31) << 2;
            *(float4*)&Ais[r][q] = *(const float4*)(A + (size_t)(i0 + r) * DD + q);
            *(float4*)&Aks[r][q] = *(const float4*)(A + (size_t)(k0 + r) * DD + q);
        }
        __syncthreads();
        if (t < 256) {
            const int u = t & 15, v = t >> 4;
            float a00 = 0.f, a01 = 0.f, a10 = 0.f, a11 = 0.f;
#pragma unroll 4
            for (int d = 0; d < DD; d += 4) {
                const float4 i0v = *(const float4*)&Ais[v][d];
                const float4 i1v = *(const float4*)&Ais[v + 16][d];
                const float4 k0v = *(const float4*)&Aks[u][d];
                const float4 k1v = *(const float4*)&Aks[u + 16][d];
                a00 = fmaf(i0v.x, k0v.x, a00); a00 = fmaf(i0v.y, k0v.y, a00);
                a00 = fmaf(i0v.z, k0v.z, a00); a00 = fmaf(i0v.w, k0v.w, a00);
                a01 = fmaf(i0v.x, k1v.x, a01); a01 = fmaf(i0v.y, k1v.y, a01);
                a01 = fmaf(i0v.z, k1v.z, a01); a01 = fmaf(i0v.w, k1v.w, a01);
                a10 = fmaf(i1v.x, k0v.x, a10); a10 = fmaf(i1v.y, k0v.y, a10);
                a10 = fmaf(i1v.z, k0v.z, a10); a10 = fmaf(i1v.w, k0v.w, a10);
                a11 = fmaf(i1v.x, k1v.x, a11); a11 = fmaf(i1v.y, k1v.y, a11);
                a11 = fmaf(i1v.z, k1v.z, a11); a11 = fmaf(i1v.w, k1v.w, a11);
            }
#pragma unroll
            for (int a = 0; a < 2; ++a)
#pragma unroll
                for (int bb = 0; bb < 2; ++bb) {
                    const int i = i0 + v + 16 * a;
                    const int k = k0 + u + 16 * bb;
                    const float acc = a == 0 ? (bb == 0 ? a00 : a01) : (bb == 0 ? a10 : a11);
                    const float c2 = p2[i] + p2[k] - 2.f * acc;
                    const float iv = 1.f / fmaxf(2.f * sqrtf(fmaxf(c2, EPSF)), EPSF);
                    __hip_atomic_store(&invd[(size_t)i * NN + k], iv,
                                       __ATOMIC_RELAXED, __HIP_MEMORY_SCOPE_AGENT);
                    Tvs[v + 16 * a][u + 16 * bb] = iv;
                }
        }
        __syncthreads();
        if (ti != tk) {      // mirror tile: invd[k][i]
            for (int idx = t; idx < TS * TS; idx += NT2) {
                const int r = idx >> 5, c = idx & 31;     // r = k-local, c = i-local
                __hip_atomic_store(&invd[(size_t)(k0 + r) * NN + i0 + c], Tvs[c][r],
                                   __ATOMIC_RELAXED, __HIP_MEMORY_SCOPE_AGENT);
            }
        }
    }

    // ================= grid barrier =================
    __syncthreads();   // all lanes' stores complete (waitcnt) before the release-add
    if (t == 0) {
        __hip_atomic_fetch_add(bar, 1, __ATOMIC_ACQ_REL, __HIP_MEMORY_SCOPE_AGENT);
        while (__hip_atomic_load(bar, __ATOMIC_ACQUIRE, __HIP_MEMORY_SCOPE_AGENT) < NB2)
            __builtin_amdgcn_s_sleep(2);
    }
    __syncthreads();

    // ================= Phase B: cube =================
    for (int rep = 0; rep < 3; ++rep) {
        const int i = bidx + rep * NB2;
        if (i >= NN) break;
        const int yi = y[i];
        if (t == 0) cnt = 0;
        if (t < DD / 4) ((float4*)Bsr)[t] = ((const float4*)(B + (size_t)i * DD))[t];
        __syncthreads();

        // csmd[i][t] on the fly
        float dot = 0.f;
        const float* brow = B + (size_t)t * DD;
#pragma unroll 4
        for (int d = 0; d < DD; d += 4) {
            const float4 bv = *(const float4*)(brow + d);
            dot = fmaf(bv.x, Bsr[d + 0], dot);
            dot = fmaf(bv.y, Bsr[d + 1], dot);
            dot = fmaf(bv.z, Bsr[d + 2], dot);
            dot = fmaf(bv.w, Bsr[d + 3], dot);
        }
        const float cit = prod[i] + prod[t] - 2.f * dot;
        const int yt = y[t];
        if (yt == yi && t != i) {
            const int p = atomicAdd(&cnt, 1);
            cvals[p] = cit;
            jidx[p]  = t;
        }
        __syncthreads();
        const int c = cnt;
        float m = 0.f;
        const float* invcol = invd + t;
#pragma unroll 4
        for (int jj = 0; jj < c; ++jj) {
            const float dlt = fmaxf(cit - cvals[jj], 0.f);
            const float iv = __hip_atomic_load(&invcol[(size_t)jidx[jj] * NN],
                                               __ATOMIC_RELAXED, __HIP_MEMORY_SCOPE_AGENT);
            m = fmaxf(m, dlt * iv);
        }
        if (yt == yi) m = __builtin_inff();
        red[t] = m;
        __syncthreads();
        if (t < 128) red[t] = fminf(red[t], fminf(red[t + 128], red[t + 256]));
        __syncthreads();
        if (t < 64) {
            float v = fminf(red[t], red[t + 64]);
#pragma unroll
            for (int off = 32; off > 0; off >>= 1)
                v = fminf(v, __shfl_down(v, off));
            if (t == 0) out[i] = v;
        }
        __syncthreads();
    }
}

extern "C" void kernel_launch(void* const* d_in, const int* in_sizes, int n_in,
                              void* d_out, int out_size, void* d_ws, size_t ws_size,
                              hipStream_t stream) {
    const float* X = (const float*)d_in[0];
    const float* G = (const float*)d_in[1];
    const int*   y = (const int*)d_in[2];

    float* ws   = (float*)d_ws;
    float* B    = ws;                  // 384*128
    float* A    = B + NN * DD;         // 384*128
    float* prod = A + NN * DD;         // 384
    float* p2   = prod + NN;           // 384
    float* invd = p2 + NN;             // 384*384
    int*   bar  = (int*)(invd + NN * NN);
    float* out  = (float*)d_out;

    k_A    <<<dim3(NN), dim3(DD), 0, stream>>>(X, G, B, A, prod, p2, bar);
    k_fused<<<dim3(NB2), dim3(NT2), 0, stream>>>(B, A, prod, p2, y, invd, bar, out);
}